// Round 9
// baseline (586.211 us; speedup 1.0000x reference)
//
#include <hip/hip_runtime.h>
#include <hip/hip_bf16.h>

// ---------------------------------------------------------------------------
// GCN forward, round 9.
//   k_mfma: R8 GEMM (128x128, BK=32, 4 waves 64x64, unit-XOR swizzle on the
//           global source, linear LDS dest, XCD-bijective 1D remap)
//           + DOUBLE-BUFFERED LDS with stage-ahead (T3 minimum 2-phase):
//           STAGE(buf^1, k+1) issued BEFORE COMPUTE(buf, k); single
//           vmcnt-drain per K-step via __syncthreads after MFMA.
//           Static buffer names (two explicit half-iterations per loop).
//   k_agg:  frozen R8 full-row gather (declared at delivery roofline).
// ---------------------------------------------------------------------------

#define THREADS 256

typedef __bf16 bf16_t;
typedef __bf16 bf16x8 __attribute__((ext_vector_type(8)));
typedef __bf16 bf16x4 __attribute__((ext_vector_type(4)));
typedef float  f32x4  __attribute__((ext_vector_type(4)));

typedef const __attribute__((address_space(1))) void* gas_ptr;
typedef __attribute__((address_space(3))) void*       las_ptr;

// ------------------------------ CSR build ----------------------------------

__global__ void k_zero_int(int* __restrict__ p, int n) {
    int i = blockIdx.x * blockDim.x + threadIdx.x;
    if (i < n) p[i] = 0;
}

__global__ void k_count(const int* __restrict__ dst, int* __restrict__ cnt, int E, int n) {
    int i = blockIdx.x * blockDim.x + threadIdx.x;
    if (i < E) {
        int d = dst[i];
        if ((unsigned)d < (unsigned)n) atomicAdd(&cnt[d], 1);
    }
}

__global__ void k_dinv(const int* __restrict__ cnt, float* __restrict__ dinv, int n) {
    int i = blockIdx.x * blockDim.x + threadIdx.x;
    if (i < n) dinv[i] = rsqrtf((float)(cnt[i] + 1));   // +1 self-loop
}

__global__ __launch_bounds__(1024) void k_scan(const int* __restrict__ cnt,
                                               int* __restrict__ row_ptr,
                                               int* __restrict__ cursor, int n)
{
    __shared__ int sm[1024];
    const int t = threadIdx.x;
    const int chunk = (n + 1023) >> 10;
    const int lo = t * chunk, hi = min(n, lo + chunk);
    int s = 0;
    for (int i = lo; i < hi; ++i) s += cnt[i];
    sm[t] = s;
    __syncthreads();
    for (int off = 1; off < 1024; off <<= 1) {
        int v = (t >= off) ? sm[t - off] : 0;
        __syncthreads();
        sm[t] += v;
        __syncthreads();
    }
    int run = sm[t] - s;
    for (int i = lo; i < hi; ++i) {
        row_ptr[i] = run;
        cursor[i]  = run;
        run += cnt[i];
    }
}

__global__ void k_fill(const int* __restrict__ src, const int* __restrict__ dst,
                       const float* __restrict__ dinv, int* __restrict__ cursor,
                       int2* __restrict__ ew, int E, int n)
{
    int i = blockIdx.x * blockDim.x + threadIdx.x;
    if (i < E) {
        int s = src[i], d = dst[i];
        if ((unsigned)s >= (unsigned)n || (unsigned)d >= (unsigned)n) return;
        int pos = atomicAdd(&cursor[d], 1);
        ew[pos] = make_int2(s, __float_as_int(dinv[s]));
    }
}

// --------------------------- f32 -> hi/lo bf16 -----------------------------

__global__ void k_split(const float* __restrict__ in, bf16_t* __restrict__ hi,
                        bf16_t* __restrict__ lo, int n4)
{
    int i = blockIdx.x * blockDim.x + threadIdx.x;
    const int stride = gridDim.x * blockDim.x;
    for (; i < n4; i += stride) {
        float4 v = ((const float4*)in)[i];
        bf16x4 h, l;
        h[0] = (bf16_t)v.x; l[0] = (bf16_t)(v.x - (float)h[0]);
        h[1] = (bf16_t)v.y; l[1] = (bf16_t)(v.y - (float)h[1]);
        h[2] = (bf16_t)v.z; l[2] = (bf16_t)(v.z - (float)h[2]);
        h[3] = (bf16_t)v.w; l[3] = (bf16_t)(v.w - (float)h[3]);
        ((bf16x4*)hi)[i] = h;
        ((bf16x4*)lo)[i] = l;
    }
}

// ------------------------ split-bf16 MFMA GEMM -----------------------------
// C(MxN, f32) = (Ah+Al)(MxK) @ (Bh+Bl)(NxK)^T, dropping Al*Bl.
// Tile 128x128, BK=32, 256 threads = 4 waves (2m x 2n), 64x64 each.
// XCD-bijective 1D remap (m204). Double-buffered LDS, stage-ahead 2-phase:
// per half-step: STAGE(other buf, next k) -> ds_read+MFMA(this buf) ->
// __syncthreads (drains the prefetch under the compute just done).
__global__ __launch_bounds__(256) void k_mfma(
    const bf16_t* __restrict__ Ah, const bf16_t* __restrict__ Al,
    const bf16_t* __restrict__ Bh, const bf16_t* __restrict__ Bl,
    float* __restrict__ C, int M, int N, int K, int ntn)
{
    __shared__ bf16_t sAh0[128 * 32], sAl0[128 * 32], sBh0[128 * 32], sBl0[128 * 32];
    __shared__ bf16_t sAh1[128 * 32], sAl1[128 * 32], sBh1[128 * 32], sBl1[128 * 32];

    // --- XCD-bijective logical tile id (m204) ---
    const int nwg = gridDim.x;
    const int q   = nwg >> 3, r = nwg & 7;
    const int xcd = blockIdx.x & 7;
    const int idx = blockIdx.x >> 3;
    const int L   = (xcd < r ? xcd * (q + 1) : r * (q + 1) + (xcd - r) * q) + idx;
    const int rt  = L / ntn;           // row-tile (panel-major)
    const int ct  = L - rt * ntn;      // column-tile

    const int tid  = threadIdx.x;
    const int lane = tid & 63;
    const int wid  = tid >> 6;
    const int m0   = rt * 128;
    const int n0   = ct * 128;
    const int wm   = (wid >> 1) * 64;
    const int wn   = (wid & 1) * 64;

    f32x4 acc[4][4] = {};

    int asrc[2], bsrc[2], sdst[2];
#pragma unroll
    for (int i = 0; i < 2; ++i) {
        int p    = i * 256 + tid;
        int unit = p >> 3, sl = p & 7;
        int u    = sl ^ (unit & 7);
        int row  = (unit << 1) | (u >> 2);
        int kb   = u & 3;
        int gm   = m0 + row; if (gm >= M) gm = M - 1;   // clamp tail rows
        asrc[i]  = gm * K + kb * 8;
        bsrc[i]  = (n0 + row) * K + kb * 8;
        sdst[i]  = p * 8;                                // bf16 elems
    }

#define STAGE(SAH, SAL, SBH, SBL, KOFF)                                           \
    do {                                                                          \
        _Pragma("unroll")                                                         \
        for (int i = 0; i < 2; ++i) {                                             \
            __builtin_amdgcn_global_load_lds((gas_ptr)(Ah + asrc[i] + (KOFF)),    \
                                             (las_ptr)(SAH + sdst[i]), 16, 0, 0); \
            __builtin_amdgcn_global_load_lds((gas_ptr)(Al + asrc[i] + (KOFF)),    \
                                             (las_ptr)(SAL + sdst[i]), 16, 0, 0); \
            __builtin_amdgcn_global_load_lds((gas_ptr)(Bh + bsrc[i] + (KOFF)),    \
                                             (las_ptr)(SBH + sdst[i]), 16, 0, 0); \
            __builtin_amdgcn_global_load_lds((gas_ptr)(Bl + bsrc[i] + (KOFF)),    \
                                             (las_ptr)(SBL + sdst[i]), 16, 0, 0); \
        }                                                                         \
    } while (0)

#define COMPUTE(SAH, SAL, SBH, SBL)                                               \
    do {                                                                          \
        const int kb = lane >> 4;                                                 \
        bf16x8 a_h[4], a_l[4], b_h[4], b_l[4];                                    \
        _Pragma("unroll")                                                         \
        for (int mf = 0; mf < 4; ++mf) {                                          \
            int row  = wm + mf * 16 + (lane & 15);                                \
            int unit = row >> 1;                                                  \
            int sl   = (((row & 1) << 2) | kb) ^ (unit & 7);                      \
            int off  = (unit * 8 + sl) * 8;                                       \
            a_h[mf] = *(const bf16x8*)(SAH + off);                                \
            a_l[mf] = *(const bf16x8*)(SAL + off);                                \
        }                                                                         \
        _Pragma("unroll")                                                         \
        for (int nf = 0; nf < 4; ++nf) {                                          \
            int row  = wn + nf * 16 + (lane & 15);                                \
            int unit = row >> 1;                                                  \
            int sl   = (((row & 1) << 2) | kb) ^ (unit & 7);                      \
            int off  = (unit * 8 + sl) * 8;                                       \
            b_h[nf] = *(const bf16x8*)(SBH + off);                                \
            b_l[nf] = *(const bf16x8*)(SBL + off);                                \
        }                                                                         \
        _Pragma("unroll")                                                         \
        for (int mf = 0; mf < 4; ++mf)                                            \
            _Pragma("unroll")                                                     \
            for (int nf = 0; nf < 4; ++nf) {                                      \
                acc[mf][nf] = __builtin_amdgcn_mfma_f32_16x16x32_bf16(            \
                    a_h[mf], b_h[nf], acc[mf][nf], 0, 0, 0);                      \
                acc[mf][nf] = __builtin_amdgcn_mfma_f32_16x16x32_bf16(            \
                    a_l[mf], b_h[nf], acc[mf][nf], 0, 0, 0);                      \
                acc[mf][nf] = __builtin_amdgcn_mfma_f32_16x16x32_bf16(            \
                    a_h[mf], b_l[nf], acc[mf][nf], 0, 0, 0);                      \
            }                                                                     \
    } while (0)

    // prologue: fill buf0 with k=0
    STAGE(sAh0, sAl0, sBh0, sBl0, 0);
    __syncthreads();

    for (int k0 = 0; k0 < K; k0 += 64) {
        // even half: prefetch k0+32 into buf1, compute buf0
        if (k0 + 32 < K) STAGE(sAh1, sAl1, sBh1, sBl1, k0 + 32);
        COMPUTE(sAh0, sAl0, sBh0, sBl0);
        __syncthreads();
        // odd half: prefetch k0+64 into buf0, compute buf1
        if (k0 + 64 < K) STAGE(sAh0, sAl0, sBh0, sBl0, k0 + 64);
        COMPUTE(sAh1, sAl1, sBh1, sBl1);
        __syncthreads();
    }

#undef STAGE
#undef COMPUTE

    // C/D layout: col = lane&15, row = (lane>>4)*4 + reg  [learn_hip m89/m91]
    const int cn = lane & 15;
    const int cr = (lane >> 4) * 4;
#pragma unroll
    for (int mf = 0; mf < 4; ++mf) {
#pragma unroll
        for (int r2 = 0; r2 < 4; ++r2) {
            const int m = m0 + wm + mf * 16 + cr + r2;
            if (m < M) {
                float* cp = C + (size_t)m * N + n0 + wn + cn;
                cp[0]  = acc[mf][0][r2];
                cp[16] = acc[mf][1][r2];
                cp[32] = acc[mf][2][r2];
                cp[48] = acc[mf][3][r2];
            }
        }
    }
}

// --------------------------- gather-aggregate ------------------------------
// Out[r] = dinv[r]*( sum_e w_e*Lin[col_e] ) + dinv[r]^2*Lin[r]
// Full-row per wave (NV4 float4 per lane), simple edge loop (frozen, R8).
// MODE 1: +bias, ReLU, write hi/lo bf16 pair. MODE 0: +bias, softmax, f32.
template <int NV4, int MODE>
__global__ __launch_bounds__(256) void k_agg(
    const float* __restrict__ Lin, float* __restrict__ OutF,
    bf16_t* __restrict__ OutH, bf16_t* __restrict__ OutL,
    const int* __restrict__ row_ptr, const int* __restrict__ cnt,
    const int2* __restrict__ ew, const float* __restrict__ dinv,
    const float* __restrict__ bias, int M)
{
    const int D = NV4 * 256;
    const int row = blockIdx.x * 4 + (threadIdx.x >> 6);
    if (row >= M) return;
    const int lane = threadIdx.x & 63;

    const float dr  = dinv[row];
    const int   beg = row_ptr[row];
    const int   num = cnt[row];

    float4 acc[NV4];
#pragma unroll
    for (int j = 0; j < NV4; ++j) acc[j] = make_float4(0.f, 0.f, 0.f, 0.f);

    for (int e = 0; e < num; ++e) {
        const int2 ee = ew[beg + e];
        const float w = __int_as_float(ee.y);
        const float4* p = (const float4*)(Lin + (size_t)ee.x * D) + lane;
#pragma unroll
        for (int j = 0; j < NV4; ++j) {
            float4 v = p[j * 64];
            acc[j].x += w * v.x; acc[j].y += w * v.y;
            acc[j].z += w * v.z; acc[j].w += w * v.w;
        }
    }

    const float4* ps = (const float4*)(Lin + (size_t)row * D) + lane;
    const float dr2 = dr * dr;

    if (MODE == 1) {
#pragma unroll
        for (int j = 0; j < NV4; ++j) {
            float4 v = ps[j * 64];
            const float4 b = ((const float4*)bias)[j * 64 + lane];
            float4 o;
            o.x = fmaxf(acc[j].x * dr + dr2 * v.x + b.x, 0.f);
            o.y = fmaxf(acc[j].y * dr + dr2 * v.y + b.y, 0.f);
            o.z = fmaxf(acc[j].z * dr + dr2 * v.z + b.z, 0.f);
            o.w = fmaxf(acc[j].w * dr + dr2 * v.w + b.w, 0.f);
            bf16x4 h, l;
            h[0] = (bf16_t)o.x; l[0] = (bf16_t)(o.x - (float)h[0]);
            h[1] = (bf16_t)o.y; l[1] = (bf16_t)(o.y - (float)h[1]);
            h[2] = (bf16_t)o.z; l[2] = (bf16_t)(o.z - (float)h[2]);
            h[3] = (bf16_t)o.w; l[3] = (bf16_t)(o.w - (float)h[3]);
            const size_t eo = (size_t)row * D + lane * 4 + j * 256;
            *(bf16x4*)(OutH + eo) = h;
            *(bf16x4*)(OutL + eo) = l;
        }
    } else {
        float4 v = ps[0];
        const float4 b = ((const float4*)bias)[lane];
        float4 o;
        o.x = acc[0].x * dr + dr2 * v.x + b.x;
        o.y = acc[0].y * dr + dr2 * v.y + b.y;
        o.z = acc[0].z * dr + dr2 * v.z + b.z;
        o.w = acc[0].w * dr + dr2 * v.w + b.w;
        float mx = fmaxf(fmaxf(o.x, o.y), fmaxf(o.z, o.w));
#pragma unroll
        for (int off = 32; off > 0; off >>= 1) mx = fmaxf(mx, __shfl_xor(mx, off));
        float e0 = expf(o.x - mx), e1 = expf(o.y - mx),
              e2 = expf(o.z - mx), e3 = expf(o.w - mx);
        float s = e0 + e1 + e2 + e3;
#pragma unroll
        for (int off = 32; off > 0; off >>= 1) s += __shfl_xor(s, off);
        const float inv = 1.0f / s;
        ((float4*)(OutF + (size_t)row * D))[lane] =
            make_float4(e0 * inv, e1 * inv, e2 * inv, e3 * inv);
    }
}

// ------------------------------- launcher ----------------------------------

extern "C" void kernel_launch(void* const* d_in, const int* in_sizes, int n_in,
                              void* d_out, int out_size, void* d_ws, size_t ws_size,
                              hipStream_t stream)
{
    const float* x    = (const float*)d_in[0];
    const int*   eidx = (const int*)d_in[1];      // int32 [2][E]
    const float* W1 = (const float*)d_in[2]; const float* b1 = (const float*)d_in[3];
    const float* W2 = (const float*)d_in[4]; const float* b2 = (const float*)d_in[5];
    const float* W3 = (const float*)d_in[6]; const float* b3 = (const float*)d_in[7];
    const float* W4 = (const float*)d_in[8]; const float* b4 = (const float*)d_in[9];

    const int M = in_sizes[0] / 512;     // 20000
    const int E = in_sizes[1] / 2;       // 320000
    const int DH = 512, DO = 256;

    const int* srcI = eidx;
    const int* dstI = eidx + E;

    // ---- workspace layout (bytes) ----
    char* ws = (char*)d_ws;
    int*    cnt     = (int*)   (ws + 0);                  // 80KB
    int*    row_ptr = (int*)   (ws + (1 << 17));
    int*    cursor  = (int*)   (ws + (2 << 17));
    float*  dinv    = (float*) (ws + (3 << 17));
    int2*   ew      = (int2*)  (ws + 655360);             // 2.56MB
    bf16_t* W1h = (bf16_t*)(ws + 4194304);
    bf16_t* W1l = (bf16_t*)(ws + 4718592);
    bf16_t* W2h = (bf16_t*)(ws + 5242880);
    bf16_t* W2l = (bf16_t*)(ws + 5767168);
    bf16_t* W3h = (bf16_t*)(ws + 6291456);
    bf16_t* W3l = (bf16_t*)(ws + 6815744);
    bf16_t* W4h = (bf16_t*)(ws + 7340032);
    bf16_t* W4l = (bf16_t*)(ws + 7602176);
    const size_t HALF = (size_t)20000 * 512 * 2;          // 20.48MB
    bf16_t* PH  = (bf16_t*)(ws + 7864320);                // activation pair (hi)
    bf16_t* PL  = (bf16_t*)(ws + 7864320 + HALF);         // activation pair (lo)
    float*  Lin = (float*) (ws + 7864320 + 2 * HALF);     // f32 GEMM out, 41MB
    float*  out = (float*)d_out;

    const int gN = (M + THREADS - 1) / THREADS;
    const int gE = (E + THREADS - 1) / THREADS;
    const int nRT   = (M + 127) / 128;                    // 157 row tiles
    const int gemmH = nRT * (DH / 128);                   // 628 (1D, remapped)
    const int gemmO = nRT * (DO / 128);                   // 314
    const int gAgg  = (M + 3) / 4;

    // ---- CSR build ----
    k_zero_int<<<gN, THREADS, 0, stream>>>(cnt, M);
    k_count   <<<gE, THREADS, 0, stream>>>(dstI, cnt, E, M);
    k_dinv    <<<gN, THREADS, 0, stream>>>(cnt, dinv, M);
    k_scan    <<<1, 1024, 0, stream>>>(cnt, row_ptr, cursor, M);
    k_fill    <<<gE, THREADS, 0, stream>>>(srcI, dstI, dinv, cursor, ew, E, M);

    // ---- operand splits ----
    k_split<<<2048, THREADS, 0, stream>>>(x,  PH,  PL,  M * DH / 4);
    k_split<<<256,  THREADS, 0, stream>>>(W1, W1h, W1l, DH * DH / 4);
    k_split<<<256,  THREADS, 0, stream>>>(W2, W2h, W2l, DH * DH / 4);
    k_split<<<256,  THREADS, 0, stream>>>(W3, W3h, W3l, DH * DH / 4);
    k_split<<<128,  THREADS, 0, stream>>>(W4, W4h, W4l, DO * DH / 4);

    // ---- Layer 1 ----
    k_mfma<<<gemmH, THREADS, 0, stream>>>(PH, PL, W1h, W1l, Lin, M, DH, 512, DH / 128);
    k_agg<2, 1><<<gAgg, THREADS, 0, stream>>>(Lin, nullptr, PH, PL, row_ptr, cnt, ew, dinv, b1, M);
    // ---- Layer 2 ----
    k_mfma<<<gemmH, THREADS, 0, stream>>>(PH, PL, W2h, W2l, Lin, M, DH, DH, DH / 128);
    k_agg<2, 1><<<gAgg, THREADS, 0, stream>>>(Lin, nullptr, PH, PL, row_ptr, cnt, ew, dinv, b2, M);
    // ---- Layer 3 ----
    k_mfma<<<gemmH, THREADS, 0, stream>>>(PH, PL, W3h, W3l, Lin, M, DH, DH, DH / 128);
    k_agg<2, 1><<<gAgg, THREADS, 0, stream>>>(Lin, nullptr, PH, PL, row_ptr, cnt, ew, dinv, b3, M);
    // ---- Layer 4 (fused bias+softmax in agg epilogue) ----
    k_mfma<<<gemmO, THREADS, 0, stream>>>(PH, PL, W4h, W4l, Lin, M, DO, DH, DO / 128);
    k_agg<1, 0><<<gAgg, THREADS, 0, stream>>>(Lin, out, nullptr, nullptr, row_ptr, cnt, ew, dinv, b4, M);
}

// Round 10
// 537.464 us; speedup vs baseline: 1.0907x; 1.0907x over previous
//
#include <hip/hip_runtime.h>
#include <hip/hip_bf16.h>

// ---------------------------------------------------------------------------
// GCN forward, round 10.
//   k_mfma: EXACT R8 GEMM (128x128, BK=32, single-buffer, unit-XOR swizzle on
//           global source, linear LDS dest, XCD-bijective 1D remap). R9's
//           explicit dbuf was null (m99/m100 reproduced) — reverted.
//   k_agg_h: XCD-keyed 64-col slice (slice = bid&7 -> per-XCD footprint
//           5.1MB ~ L2)  x  8-edge-parallel lanes (32B/lane/iter, R4's MLP).
//           shfl_xor tree folds edge-groups; lanes 0-7 do fused
//           bias+ReLU+hi/lo epilogue.
//   k_agg_o: same for layer 4 (4 slices, raw f32 logits) + k_softmax_bias.
// ---------------------------------------------------------------------------

#define THREADS 256

typedef __bf16 bf16_t;
typedef __bf16 bf16x8 __attribute__((ext_vector_type(8)));
typedef __bf16 bf16x4 __attribute__((ext_vector_type(4)));
typedef float  f32x4  __attribute__((ext_vector_type(4)));

typedef const __attribute__((address_space(1))) void* gas_ptr;
typedef __attribute__((address_space(3))) void*       las_ptr;

// ------------------------------ CSR build ----------------------------------

__global__ void k_zero_int(int* __restrict__ p, int n) {
    int i = blockIdx.x * blockDim.x + threadIdx.x;
    if (i < n) p[i] = 0;
}

__global__ void k_count(const int* __restrict__ dst, int* __restrict__ cnt, int E, int n) {
    int i = blockIdx.x * blockDim.x + threadIdx.x;
    if (i < E) {
        int d = dst[i];
        if ((unsigned)d < (unsigned)n) atomicAdd(&cnt[d], 1);
    }
}

__global__ void k_dinv(const int* __restrict__ cnt, float* __restrict__ dinv, int n) {
    int i = blockIdx.x * blockDim.x + threadIdx.x;
    if (i < n) dinv[i] = rsqrtf((float)(cnt[i] + 1));   // +1 self-loop
}

__global__ __launch_bounds__(1024) void k_scan(const int* __restrict__ cnt,
                                               int* __restrict__ row_ptr,
                                               int* __restrict__ cursor, int n)
{
    __shared__ int sm[1024];
    const int t = threadIdx.x;
    const int chunk = (n + 1023) >> 10;
    const int lo = t * chunk, hi = min(n, lo + chunk);
    int s = 0;
    for (int i = lo; i < hi; ++i) s += cnt[i];
    sm[t] = s;
    __syncthreads();
    for (int off = 1; off < 1024; off <<= 1) {
        int v = (t >= off) ? sm[t - off] : 0;
        __syncthreads();
        sm[t] += v;
        __syncthreads();
    }
    int run = sm[t] - s;
    for (int i = lo; i < hi; ++i) {
        row_ptr[i] = run;
        cursor[i]  = run;
        run += cnt[i];
    }
}

__global__ void k_fill(const int* __restrict__ src, const int* __restrict__ dst,
                       const float* __restrict__ dinv, int* __restrict__ cursor,
                       int2* __restrict__ ew, int E, int n)
{
    int i = blockIdx.x * blockDim.x + threadIdx.x;
    if (i < E) {
        int s = src[i], d = dst[i];
        if ((unsigned)s >= (unsigned)n || (unsigned)d >= (unsigned)n) return;
        int pos = atomicAdd(&cursor[d], 1);
        ew[pos] = make_int2(s, __float_as_int(dinv[s]));
    }
}

// --------------------------- f32 -> hi/lo bf16 -----------------------------

__global__ void k_split(const float* __restrict__ in, bf16_t* __restrict__ hi,
                        bf16_t* __restrict__ lo, int n4)
{
    int i = blockIdx.x * blockDim.x + threadIdx.x;
    const int stride = gridDim.x * blockDim.x;
    for (; i < n4; i += stride) {
        float4 v = ((const float4*)in)[i];
        bf16x4 h, l;
        h[0] = (bf16_t)v.x; l[0] = (bf16_t)(v.x - (float)h[0]);
        h[1] = (bf16_t)v.y; l[1] = (bf16_t)(v.y - (float)h[1]);
        h[2] = (bf16_t)v.z; l[2] = (bf16_t)(v.z - (float)h[2]);
        h[3] = (bf16_t)v.w; l[3] = (bf16_t)(v.w - (float)h[3]);
        ((bf16x4*)hi)[i] = h;
        ((bf16x4*)lo)[i] = l;
    }
}

// ------------------------ split-bf16 MFMA GEMM (R8) ------------------------
// C(MxN, f32) = (Ah+Al)(MxK) @ (Bh+Bl)(NxK)^T, dropping Al*Bl.
// Tile 128x128, BK=32, 256 threads = 4 waves (2m x 2n), 64x64 each.
// 1D grid + XCD-bijective remap (m204).
__global__ __launch_bounds__(256) void k_mfma(
    const bf16_t* __restrict__ Ah, const bf16_t* __restrict__ Al,
    const bf16_t* __restrict__ Bh, const bf16_t* __restrict__ Bl,
    float* __restrict__ C, int M, int N, int K, int ntn)
{
    __shared__ bf16_t sAh[128 * 32];
    __shared__ bf16_t sAl[128 * 32];
    __shared__ bf16_t sBh[128 * 32];
    __shared__ bf16_t sBl[128 * 32];

    // --- XCD-bijective logical tile id (m204) ---
    const int nwg = gridDim.x;
    const int q   = nwg >> 3, r = nwg & 7;
    const int xcd = blockIdx.x & 7;
    const int idx = blockIdx.x >> 3;
    const int L   = (xcd < r ? xcd * (q + 1) : r * (q + 1) + (xcd - r) * q) + idx;
    const int rt  = L / ntn;           // row-tile (panel-major)
    const int ct  = L - rt * ntn;      // column-tile

    const int tid  = threadIdx.x;
    const int lane = tid & 63;
    const int wid  = tid >> 6;
    const int m0   = rt * 128;
    const int n0   = ct * 128;
    const int wm   = (wid >> 1) * 64;
    const int wn   = (wid & 1) * 64;

    f32x4 acc[4][4] = {};

    int asrc[2], bsrc[2], sdst[2];
#pragma unroll
    for (int i = 0; i < 2; ++i) {
        int p    = i * 256 + tid;
        int unit = p >> 3, sl = p & 7;
        int u    = sl ^ (unit & 7);
        int row  = (unit << 1) | (u >> 2);
        int kb   = u & 3;
        int gm   = m0 + row; if (gm >= M) gm = M - 1;   // clamp tail rows
        asrc[i]  = gm * K + kb * 8;
        bsrc[i]  = (n0 + row) * K + kb * 8;
        sdst[i]  = p * 8;                                // bf16 elems
    }

    for (int k0 = 0; k0 < K; k0 += 32) {
#pragma unroll
        for (int i = 0; i < 2; ++i) {
            __builtin_amdgcn_global_load_lds((gas_ptr)(Ah + asrc[i] + k0),
                                             (las_ptr)(sAh + sdst[i]), 16, 0, 0);
            __builtin_amdgcn_global_load_lds((gas_ptr)(Al + asrc[i] + k0),
                                             (las_ptr)(sAl + sdst[i]), 16, 0, 0);
            __builtin_amdgcn_global_load_lds((gas_ptr)(Bh + bsrc[i] + k0),
                                             (las_ptr)(sBh + sdst[i]), 16, 0, 0);
            __builtin_amdgcn_global_load_lds((gas_ptr)(Bl + bsrc[i] + k0),
                                             (las_ptr)(sBl + sdst[i]), 16, 0, 0);
        }
        __syncthreads();

        const int kb = lane >> 4;
        bf16x8 a_h[4], a_l[4], b_h[4], b_l[4];
#pragma unroll
        for (int mf = 0; mf < 4; ++mf) {
            int row  = wm + mf * 16 + (lane & 15);
            int unit = row >> 1;
            int sl   = (((row & 1) << 2) | kb) ^ (unit & 7);
            int off  = (unit * 8 + sl) * 8;
            a_h[mf] = *(const bf16x8*)(sAh + off);
            a_l[mf] = *(const bf16x8*)(sAl + off);
        }
#pragma unroll
        for (int nf = 0; nf < 4; ++nf) {
            int row  = wn + nf * 16 + (lane & 15);
            int unit = row >> 1;
            int sl   = (((row & 1) << 2) | kb) ^ (unit & 7);
            int off  = (unit * 8 + sl) * 8;
            b_h[nf] = *(const bf16x8*)(sBh + off);
            b_l[nf] = *(const bf16x8*)(sBl + off);
        }
#pragma unroll
        for (int mf = 0; mf < 4; ++mf)
#pragma unroll
            for (int nf = 0; nf < 4; ++nf) {
                acc[mf][nf] = __builtin_amdgcn_mfma_f32_16x16x32_bf16(
                    a_h[mf], b_h[nf], acc[mf][nf], 0, 0, 0);
                acc[mf][nf] = __builtin_amdgcn_mfma_f32_16x16x32_bf16(
                    a_l[mf], b_h[nf], acc[mf][nf], 0, 0, 0);
                acc[mf][nf] = __builtin_amdgcn_mfma_f32_16x16x32_bf16(
                    a_h[mf], b_l[nf], acc[mf][nf], 0, 0, 0);
            }
        __syncthreads();
    }

    // C/D layout: col = lane&15, row = (lane>>4)*4 + reg  [learn_hip m89/m91]
    const int cn = lane & 15;
    const int cr = (lane >> 4) * 4;
#pragma unroll
    for (int mf = 0; mf < 4; ++mf) {
#pragma unroll
        for (int r2 = 0; r2 < 4; ++r2) {
            const int m = m0 + wm + mf * 16 + cr + r2;
            if (m < M) {
                float* cp = C + (size_t)m * N + n0 + wn + cn;
                cp[0]  = acc[mf][0][r2];
                cp[16] = acc[mf][1][r2];
                cp[32] = acc[mf][2][r2];
                cp[48] = acc[mf][3][r2];
            }
        }
    }
}

// ------------- hidden gather: XCD-keyed slice + 8-edge-parallel ------------
// slice = bid&7 (round-robin -> per-XCD footprint 20000*64*4B = 5.1MB ~ L2).
// Wave lanes = (edge-group eg 0..7) x (col-group cg 0..7); per iter each lane
// loads 2x float4 (32B) of its edge's row: R4's per-wave memory shape.
// shfl_xor(8,16,32) folds edge-partials; lanes eg==0 do the epilogue.
__global__ __launch_bounds__(256) void k_agg_h(
    const float* __restrict__ Lin,
    bf16_t* __restrict__ OutH, bf16_t* __restrict__ OutL,
    const int* __restrict__ row_ptr, const int* __restrict__ cnt,
    const int2* __restrict__ ew, const float* __restrict__ dinv,
    const float* __restrict__ bias, int M)
{
    const int s   = blockIdx.x & 7;
    const int row = (blockIdx.x >> 3) * 4 + (threadIdx.x >> 6);
    if (row >= M) return;
    const int lane = threadIdx.x & 63;
    const int eg   = lane >> 3;              // edge sub-slot
    const int cb   = s * 64 + (lane & 7) * 4; // first float4 col

    const int beg = row_ptr[row];
    const int num = cnt[row];

    float4 a0 = make_float4(0.f, 0.f, 0.f, 0.f);
    float4 a1 = make_float4(0.f, 0.f, 0.f, 0.f);
    for (int e0 = 0; e0 < num; e0 += 8) {
        const int e = e0 + eg;
        if (e < num) {
            const int2 ee = ew[beg + e];
            const float w = __int_as_float(ee.y);
            const float* p = Lin + (size_t)ee.x * 512 + cb;
            const float4 v0 = *(const float4*)p;
            const float4 v1 = *(const float4*)(p + 32);
            a0.x += w * v0.x; a0.y += w * v0.y; a0.z += w * v0.z; a0.w += w * v0.w;
            a1.x += w * v1.x; a1.y += w * v1.y; a1.z += w * v1.z; a1.w += w * v1.w;
        }
    }
#pragma unroll
    for (int off = 8; off < 64; off <<= 1) {
        a0.x += __shfl_xor(a0.x, off); a0.y += __shfl_xor(a0.y, off);
        a0.z += __shfl_xor(a0.z, off); a0.w += __shfl_xor(a0.w, off);
        a1.x += __shfl_xor(a1.x, off); a1.y += __shfl_xor(a1.y, off);
        a1.z += __shfl_xor(a1.z, off); a1.w += __shfl_xor(a1.w, off);
    }
    if (eg == 0) {
        const float dr = dinv[row], dr2 = dr * dr;
        const float* ps = Lin + (size_t)row * 512 + cb;
        const float4 v0 = *(const float4*)ps;
        const float4 v1 = *(const float4*)(ps + 32);
        const float4 b0 = *(const float4*)(bias + cb);
        const float4 b1 = *(const float4*)(bias + cb + 32);
        float o0x = fmaxf(a0.x * dr + dr2 * v0.x + b0.x, 0.f);
        float o0y = fmaxf(a0.y * dr + dr2 * v0.y + b0.y, 0.f);
        float o0z = fmaxf(a0.z * dr + dr2 * v0.z + b0.z, 0.f);
        float o0w = fmaxf(a0.w * dr + dr2 * v0.w + b0.w, 0.f);
        float o1x = fmaxf(a1.x * dr + dr2 * v1.x + b1.x, 0.f);
        float o1y = fmaxf(a1.y * dr + dr2 * v1.y + b1.y, 0.f);
        float o1z = fmaxf(a1.z * dr + dr2 * v1.z + b1.z, 0.f);
        float o1w = fmaxf(a1.w * dr + dr2 * v1.w + b1.w, 0.f);
        bf16x4 h0, l0, h1, l1;
        h0[0] = (bf16_t)o0x; l0[0] = (bf16_t)(o0x - (float)h0[0]);
        h0[1] = (bf16_t)o0y; l0[1] = (bf16_t)(o0y - (float)h0[1]);
        h0[2] = (bf16_t)o0z; l0[2] = (bf16_t)(o0z - (float)h0[2]);
        h0[3] = (bf16_t)o0w; l0[3] = (bf16_t)(o0w - (float)h0[3]);
        h1[0] = (bf16_t)o1x; l1[0] = (bf16_t)(o1x - (float)h1[0]);
        h1[1] = (bf16_t)o1y; l1[1] = (bf16_t)(o1y - (float)h1[1]);
        h1[2] = (bf16_t)o1z; l1[2] = (bf16_t)(o1z - (float)h1[2]);
        h1[3] = (bf16_t)o1w; l1[3] = (bf16_t)(o1w - (float)h1[3]);
        const size_t eo = (size_t)row * 512 + cb;
        *(bf16x4*)(OutH + eo)      = h0;
        *(bf16x4*)(OutH + eo + 32) = h1;
        *(bf16x4*)(OutL + eo)      = l0;
        *(bf16x4*)(OutL + eo + 32) = l1;
    }
}

// --------- layer-4 gather: 4 slices (constant per XCD), raw logits ---------
__global__ __launch_bounds__(256) void k_agg_o(
    const float* __restrict__ Lin, float* __restrict__ OutF,
    const int* __restrict__ row_ptr, const int* __restrict__ cnt,
    const int2* __restrict__ ew, const float* __restrict__ dinv, int M)
{
    const int s   = blockIdx.x & 3;
    const int row = (blockIdx.x >> 2) * 4 + (threadIdx.x >> 6);
    if (row >= M) return;
    const int lane = threadIdx.x & 63;
    const int eg   = lane >> 3;
    const int cb   = s * 64 + (lane & 7) * 4;

    const int beg = row_ptr[row];
    const int num = cnt[row];

    float4 a0 = make_float4(0.f, 0.f, 0.f, 0.f);
    float4 a1 = make_float4(0.f, 0.f, 0.f, 0.f);
    for (int e0 = 0; e0 < num; e0 += 8) {
        const int e = e0 + eg;
        if (e < num) {
            const int2 ee = ew[beg + e];
            const float w = __int_as_float(ee.y);
            const float* p = Lin + (size_t)ee.x * 256 + cb;
            const float4 v0 = *(const float4*)p;
            const float4 v1 = *(const float4*)(p + 32);
            a0.x += w * v0.x; a0.y += w * v0.y; a0.z += w * v0.z; a0.w += w * v0.w;
            a1.x += w * v1.x; a1.y += w * v1.y; a1.z += w * v1.z; a1.w += w * v1.w;
        }
    }
#pragma unroll
    for (int off = 8; off < 64; off <<= 1) {
        a0.x += __shfl_xor(a0.x, off); a0.y += __shfl_xor(a0.y, off);
        a0.z += __shfl_xor(a0.z, off); a0.w += __shfl_xor(a0.w, off);
        a1.x += __shfl_xor(a1.x, off); a1.y += __shfl_xor(a1.y, off);
        a1.z += __shfl_xor(a1.z, off); a1.w += __shfl_xor(a1.w, off);
    }
    if (eg == 0) {
        const float dr = dinv[row], dr2 = dr * dr;
        const float* ps = Lin + (size_t)row * 256 + cb;
        const float4 v0 = *(const float4*)ps;
        const float4 v1 = *(const float4*)(ps + 32);
        float4 o0, o1;
        o0.x = a0.x * dr + dr2 * v0.x;  o0.y = a0.y * dr + dr2 * v0.y;
        o0.z = a0.z * dr + dr2 * v0.z;  o0.w = a0.w * dr + dr2 * v0.w;
        o1.x = a1.x * dr + dr2 * v1.x;  o1.y = a1.y * dr + dr2 * v1.y;
        o1.z = a1.z * dr + dr2 * v1.z;  o1.w = a1.w * dr + dr2 * v1.w;
        float* po = OutF + (size_t)row * 256 + cb;
        *(float4*)po        = o0;
        *(float4*)(po + 32) = o1;
    }
}

// ---------------- in-place softmax over rows of 256 (+ bias) ---------------
__global__ __launch_bounds__(256) void k_softmax_bias(float* __restrict__ IO,
                                                      const float* __restrict__ bias, int M)
{
    int row  = blockIdx.x * 4 + (threadIdx.x >> 6);
    int lane = threadIdx.x & 63;
    if (row >= M) return;
    float* p = IO + (size_t)row * 256 + lane * 4;
    float4 v = *(float4*)p;
    const float4 b = *(const float4*)(bias + lane * 4);
    v.x += b.x; v.y += b.y; v.z += b.z; v.w += b.w;
    float m = fmaxf(fmaxf(v.x, v.y), fmaxf(v.z, v.w));
#pragma unroll
    for (int off = 32; off > 0; off >>= 1) m = fmaxf(m, __shfl_xor(m, off));
    float e0 = expf(v.x - m), e1 = expf(v.y - m), e2 = expf(v.z - m), e3 = expf(v.w - m);
    float s = e0 + e1 + e2 + e3;
#pragma unroll
    for (int off = 32; off > 0; off >>= 1) s += __shfl_xor(s, off);
    float inv = 1.0f / s;
    v.x = e0 * inv; v.y = e1 * inv; v.z = e2 * inv; v.w = e3 * inv;
    *(float4*)p = v;
}

// ------------------------------- launcher ----------------------------------

extern "C" void kernel_launch(void* const* d_in, const int* in_sizes, int n_in,
                              void* d_out, int out_size, void* d_ws, size_t ws_size,
                              hipStream_t stream)
{
    const float* x    = (const float*)d_in[0];
    const int*   eidx = (const int*)d_in[1];      // int32 [2][E]
    const float* W1 = (const float*)d_in[2]; const float* b1 = (const float*)d_in[3];
    const float* W2 = (const float*)d_in[4]; const float* b2 = (const float*)d_in[5];
    const float* W3 = (const float*)d_in[6]; const float* b3 = (const float*)d_in[7];
    const float* W4 = (const float*)d_in[8]; const float* b4 = (const float*)d_in[9];

    const int M = in_sizes[0] / 512;     // 20000
    const int E = in_sizes[1] / 2;       // 320000
    const int DH = 512, DO = 256;

    const int* srcI = eidx;
    const int* dstI = eidx + E;

    // ---- workspace layout (bytes) ----
    char* ws = (char*)d_ws;
    int*    cnt     = (int*)   (ws + 0);                  // 80KB
    int*    row_ptr = (int*)   (ws + (1 << 17));
    int*    cursor  = (int*)   (ws + (2 << 17));
    float*  dinv    = (float*) (ws + (3 << 17));
    int2*   ew      = (int2*)  (ws + 655360);             // 2.56MB
    bf16_t* W1h = (bf16_t*)(ws + 4194304);
    bf16_t* W1l = (bf16_t*)(ws + 4718592);
    bf16_t* W2h = (bf16_t*)(ws + 5242880);
    bf16_t* W2l = (bf16_t*)(ws + 5767168);
    bf16_t* W3h = (bf16_t*)(ws + 6291456);
    bf16_t* W3l = (bf16_t*)(ws + 6815744);
    bf16_t* W4h = (bf16_t*)(ws + 7340032);
    bf16_t* W4l = (bf16_t*)(ws + 7602176);
    const size_t HALF = (size_t)20000 * 512 * 2;          // 20.48MB
    bf16_t* PH  = (bf16_t*)(ws + 7864320);                // activation pair (hi)
    bf16_t* PL  = (bf16_t*)(ws + 7864320 + HALF);         // activation pair (lo)
    float*  Lin = (float*) (ws + 7864320 + 2 * HALF);     // f32 GEMM out, 41MB
    float*  out = (float*)d_out;

    const int gN = (M + THREADS - 1) / THREADS;
    const int gE = (E + THREADS - 1) / THREADS;
    const int nRT   = (M + 127) / 128;                    // 157 row tiles
    const int gemmH = nRT * (DH / 128);                   // 628 (1D, remapped)
    const int gemmO = nRT * (DO / 128);                   // 314
    const int gRows = (M + 3) / 4;                        // 5000
    const int gAggH = gRows * 8;                          // 8 XCD-keyed slices
    const int gAggO = gRows * 4;                          // 4 slices

    // ---- CSR build ----
    k_zero_int<<<gN, THREADS, 0, stream>>>(cnt, M);
    k_count   <<<gE, THREADS, 0, stream>>>(dstI, cnt, E, M);
    k_dinv    <<<gN, THREADS, 0, stream>>>(cnt, dinv, M);
    k_scan    <<<1, 1024, 0, stream>>>(cnt, row_ptr, cursor, M);
    k_fill    <<<gE, THREADS, 0, stream>>>(srcI, dstI, dinv, cursor, ew, E, M);

    // ---- operand splits ----
    k_split<<<2048, THREADS, 0, stream>>>(x,  PH,  PL,  M * DH / 4);
    k_split<<<256,  THREADS, 0, stream>>>(W1, W1h, W1l, DH * DH / 4);
    k_split<<<256,  THREADS, 0, stream>>>(W2, W2h, W2l, DH * DH / 4);
    k_split<<<256,  THREADS, 0, stream>>>(W3, W3h, W3l, DH * DH / 4);
    k_split<<<128,  THREADS, 0, stream>>>(W4, W4h, W4l, DO * DH / 4);

    // ---- Layer 1 ----
    k_mfma<<<gemmH, THREADS, 0, stream>>>(PH, PL, W1h, W1l, Lin, M, DH, 512, DH / 128);
    k_agg_h<<<gAggH, THREADS, 0, stream>>>(Lin, PH, PL, row_ptr, cnt, ew, dinv, b1, M);
    // ---- Layer 2 ----
    k_mfma<<<gemmH, THREADS, 0, stream>>>(PH, PL, W2h, W2l, Lin, M, DH, DH, DH / 128);
    k_agg_h<<<gAggH, THREADS, 0, stream>>>(Lin, PH, PL, row_ptr, cnt, ew, dinv, b2, M);
    // ---- Layer 3 ----
    k_mfma<<<gemmH, THREADS, 0, stream>>>(PH, PL, W3h, W3l, Lin, M, DH, DH, DH / 128);
    k_agg_h<<<gAggH, THREADS, 0, stream>>>(Lin, PH, PL, row_ptr, cnt, ew, dinv, b3, M);
    // ---- Layer 4: sliced gather -> logits, then fused bias+softmax --------
    k_mfma<<<gemmO, THREADS, 0, stream>>>(PH, PL, W4h, W4l, Lin, M, DO, DH, DO / 128);
    k_agg_o<<<gAggO, THREADS, 0, stream>>>(Lin, out, row_ptr, cnt, ew, dinv, M);
    k_softmax_bias<<<gRows, THREADS, 0, stream>>>(out, b4, M);
}